// Round 1
// baseline (1689.773 us; speedup 1.0000x reference)
//
#include <hip/hip_runtime.h>

// GCN 2-layer, N=100000, F=64, H=128, O=100, out [N,1] fp32.
// Restructured: out = agg(relu(agg(x)@W1 + b1) . (W2@Wl)) + (b2@Wl + bl)
// agg(y)[i] = sum_{e: dst=i} dinv[src]*dinv[i]*y[src] + dinv[i]^2*y[i]

#define N_NODES 100000
#define F_IN 64
#define HID 128
#define OUT2 100

__global__ void deg_kernel(const int* __restrict__ dst, float* __restrict__ deg, int E) {
    int e = blockIdx.x * blockDim.x + threadIdx.x;
    if (e < E) atomicAdd(&deg[dst[e]], 1.0f);
}

__global__ void dinv_kernel(float* deg_dinv, int n) {
    int i = blockIdx.x * blockDim.x + threadIdx.x;
    if (i < n) deg_dinv[i] = rsqrtf(deg_dinv[i] + 1.0f);  // +1 = self-loop
}

// Layer-1 aggregation over RAW features (64 floats/node). 16 threads per edge,
// float4 gather of x[src], 4 scalar atomics into xa[dst].
__global__ void agg1_kernel(const int* __restrict__ src, const int* __restrict__ dst,
                            const float* __restrict__ dinv,
                            const float4* __restrict__ x4,
                            float* __restrict__ xa, int E) {
    long long idx = (long long)blockIdx.x * blockDim.x + threadIdx.x;
    int e = (int)(idx >> 4);
    int l = (int)(idx & 15);
    if (e >= E) return;
    int s = src[e], d = dst[e];
    float nrm = dinv[s] * dinv[d];
    float4 xv = x4[(long long)s * 16 + l];
    float* p = xa + (long long)d * F_IN + l * 4;
    atomicAdd(p + 0, xv.x * nrm);
    atomicAdd(p + 1, xv.y * nrm);
    atomicAdd(p + 2, xv.z * nrm);
    atomicAdd(p + 3, xv.w * nrm);
}

// v = W2 @ Wl  [128], c = b2.Wl + bl  (scalar)
__global__ void prep_kernel(const float* __restrict__ W2, const float* __restrict__ b2,
                            const float* __restrict__ Wl, const float* __restrict__ bl,
                            float* __restrict__ v, float* __restrict__ c) {
    int j = threadIdx.x;
    if (j < HID) {
        float acc = 0.f;
        for (int k = 0; k < OUT2; ++k) acc += W2[j * OUT2 + k] * Wl[k];
        v[j] = acc;
    }
    if (j == 0) {
        float acc = bl[0];
        for (int k = 0; k < OUT2; ++k) acc += b2[k] * Wl[k];
        *c = acc;
    }
}

// Fused: a = xa[i] + dinv^2 * x[i];  h = relu(a @ W1 + b1);  z[i] = h . v
// One wave per node. Lane L computes h[2L], h[2L+1]. W1 (32KB) + v staged in LDS.
__global__ __launch_bounds__(256) void layer1_kernel(
    const float* __restrict__ x, const float* __restrict__ xa,
    const float* __restrict__ dinv, const float* __restrict__ W1,
    const float* __restrict__ b1, const float* __restrict__ v,
    float* __restrict__ z, int n) {
    __shared__ float lW1[F_IN * HID];  // 32 KB
    __shared__ float lv[HID];
    int t = threadIdx.x;
    for (int i = t; i < F_IN * HID; i += 256) lW1[i] = W1[i];
    if (t < HID) lv[t] = v[t];
    __syncthreads();

    int lane = t & 63;
    int wave = t >> 6;
    int node = blockIdx.x * 4 + wave;
    if (node >= n) return;

    float di = dinv[node];
    long long base = (long long)node * F_IN;
    float a = xa[base + lane] + di * di * x[base + lane];

    float2 h = ((const float2*)b1)[lane];
    #pragma unroll 8
    for (int k = 0; k < F_IN; ++k) {
        float ak = __shfl(a, k, 64);
        float2 w = ((const float2*)lW1)[k * 64 + lane];
        h.x += ak * w.x;
        h.y += ak * w.y;
    }
    float2 vv = ((const float2*)lv)[lane];
    float hx = h.x > 0.f ? h.x : 0.f;
    float hy = h.y > 0.f ? h.y : 0.f;
    float zp = hx * vv.x + hy * vv.y;
    #pragma unroll
    for (int off = 32; off > 0; off >>= 1) zp += __shfl_xor(zp, off, 64);
    if (lane == 0) z[node] = zp;
}

// out[i] = dinv[i]^2 * z[i] + c   (self-loop of layer 2 + fused bias)
__global__ void outinit_kernel(const float* __restrict__ dinv, const float* __restrict__ z,
                               const float* __restrict__ c, float* __restrict__ out, int n) {
    int i = blockIdx.x * blockDim.x + threadIdx.x;
    if (i < n) { float di = dinv[i]; out[i] = di * di * z[i] + *c; }
}

// Scalar scatter for layer 2.
__global__ void agg2_kernel(const int* __restrict__ src, const int* __restrict__ dst,
                            const float* __restrict__ dinv, const float* __restrict__ z,
                            float* __restrict__ out, int E) {
    int e = blockIdx.x * blockDim.x + threadIdx.x;
    if (e < E) {
        int s = src[e], d = dst[e];
        atomicAdd(&out[d], z[s] * dinv[s] * dinv[d]);
    }
}

extern "C" void kernel_launch(void* const* d_in, const int* in_sizes, int n_in,
                              void* d_out, int out_size, void* d_ws, size_t ws_size,
                              hipStream_t stream) {
    const float* x  = (const float*)d_in[0];
    const int*   ei = (const int*)d_in[1];
    const float* W1 = (const float*)d_in[2];
    const float* b1 = (const float*)d_in[3];
    const float* W2 = (const float*)d_in[4];
    const float* b2 = (const float*)d_in[5];
    const float* Wl = (const float*)d_in[6];
    const float* bl = (const float*)d_in[7];
    float* out = (float*)d_out;

    int E = in_sizes[1] / 2;
    const int* src = ei;
    const int* dst = ei + E;

    float* ws   = (float*)d_ws;
    float* dinv = ws;                             // N
    float* xa   = ws + N_NODES;                   // N*64 (contiguous after dinv)
    float* z    = xa + (size_t)N_NODES * F_IN;    // N
    float* v    = z + N_NODES;                    // 128
    float* c    = v + HID;                        // 1

    // zero deg accumulator (aliased with dinv) + xa in one memset
    hipMemsetAsync(dinv, 0, sizeof(float) * (size_t)N_NODES * (F_IN + 1), stream);

    deg_kernel<<<(E + 255) / 256, 256, 0, stream>>>(dst, dinv, E);
    dinv_kernel<<<(N_NODES + 255) / 256, 256, 0, stream>>>(dinv, N_NODES);
    agg1_kernel<<<(int)(((long long)E * 16 + 255) / 256), 256, 0, stream>>>(
        src, dst, dinv, (const float4*)x, xa, E);
    prep_kernel<<<1, 128, 0, stream>>>(W2, b2, Wl, bl, v, c);
    layer1_kernel<<<(N_NODES + 3) / 4, 256, 0, stream>>>(x, xa, dinv, W1, b1, v, z, N_NODES);
    outinit_kernel<<<(N_NODES + 255) / 256, 256, 0, stream>>>(dinv, z, c, out, N_NODES);
    agg2_kernel<<<(E + 255) / 256, 256, 0, stream>>>(src, dst, dinv, z, out, E);
}

// Round 2
// 545.320 us; speedup vs baseline: 3.0987x; 3.0987x over previous
//
#include <hip/hip_runtime.h>

// GCN 2-layer, N=100000, F=64, H=128, O=100, out [N,1] fp32.
// out = agg(relu(agg(x)@W1 + b1) . (W2@Wl)) + (b2@Wl + bl)
// agg via CSR-by-dst GATHER (no float atomics).

#define N_NODES 100000
#define F_IN 64
#define HID 128
#define OUT2 100
#define SCAN_CHUNK 1024

__global__ void hist_kernel(const int* __restrict__ dst, int* __restrict__ cnt, int E) {
    int e = blockIdx.x * blockDim.x + threadIdx.x;
    if (e < E) atomicAdd(&cnt[dst[e]], 1);
}

__global__ void dinv_kernel(const int* __restrict__ cnt, float* __restrict__ dinv, int n) {
    int i = blockIdx.x * blockDim.x + threadIdx.x;
    if (i < n) dinv[i] = rsqrtf((float)cnt[i] + 1.0f);  // +1 = self-loop
}

// Block-level exclusive scan: each block scans SCAN_CHUNK elements (4/thread).
__global__ __launch_bounds__(256) void scan1_kernel(const int* __restrict__ cnt,
                                                    int* __restrict__ row_ptr,
                                                    int* __restrict__ bsum, int n) {
    __shared__ int lsum[256];
    int t = threadIdx.x;
    int i0 = blockIdx.x * SCAN_CHUNK + t * 4;
    int a = 0, b = 0, c = 0, d = 0;
    if (i0 < n)     a = cnt[i0];
    if (i0 + 1 < n) b = cnt[i0 + 1];
    if (i0 + 2 < n) c = cnt[i0 + 2];
    if (i0 + 3 < n) d = cnt[i0 + 3];
    int tsum = a + b + c + d;
    lsum[t] = tsum;
    __syncthreads();
    for (int off = 1; off < 256; off <<= 1) {
        int val = (t >= off) ? lsum[t - off] : 0;
        __syncthreads();
        lsum[t] += val;
        __syncthreads();
    }
    int excl = lsum[t] - tsum;
    if (i0 < n)     row_ptr[i0]     = excl;
    if (i0 + 1 < n) row_ptr[i0 + 1] = excl + a;
    if (i0 + 2 < n) row_ptr[i0 + 2] = excl + a + b;
    if (i0 + 3 < n) row_ptr[i0 + 3] = excl + a + b + c;
    if (t == 255) bsum[blockIdx.x] = lsum[255];
}

__global__ void scan2_kernel(int* __restrict__ bsum, int nb) {
    if (threadIdx.x == 0 && blockIdx.x == 0) {
        int run = 0;
        for (int i = 0; i < nb; ++i) { int t = bsum[i]; bsum[i] = run; run += t; }
    }
}

__global__ void scan3_kernel(int* __restrict__ row_ptr, const int* __restrict__ bsum,
                             int* __restrict__ cursor, int n, int E) {
    int i = blockIdx.x * blockDim.x + threadIdx.x;
    if (i < n) {
        int r = row_ptr[i] + bsum[i / SCAN_CHUNK];
        row_ptr[i] = r;
        cursor[i] = r;
    }
    if (i == 0) row_ptr[n] = E;
}

// Scatter edges into CSR slots: csr[pos] = {src, dinv[src]*dinv[dst]}
__global__ void permute_kernel(const int* __restrict__ src, const int* __restrict__ dst,
                               const float* __restrict__ dinv, int* __restrict__ cursor,
                               int2* __restrict__ csr, int E) {
    int e = blockIdx.x * blockDim.x + threadIdx.x;
    if (e < E) {
        int s = src[e], d = dst[e];
        int pos = atomicAdd(&cursor[d], 1);
        int2 m;
        m.x = s;
        m.y = __float_as_int(dinv[s] * dinv[d]);
        csr[pos] = m;
    }
}

// v = W2 @ Wl  [128], c = b2.Wl + bl  (scalar)
__global__ void prep_kernel(const float* __restrict__ W2, const float* __restrict__ b2,
                            const float* __restrict__ Wl, const float* __restrict__ bl,
                            float* __restrict__ v, float* __restrict__ c) {
    int j = threadIdx.x;
    if (j < HID) {
        float acc = 0.f;
        for (int k = 0; k < OUT2; ++k) acc += W2[j * OUT2 + k] * Wl[k];
        v[j] = acc;
    }
    if (j == 0) {
        float acc = bl[0];
        for (int k = 0; k < OUT2; ++k) acc += b2[k] * Wl[k];
        *c = acc;
    }
}

// Fused layer 1: one wave per node.
//   a[lane] = di^2*x[node,lane] + sum_in w*x[src,lane]   (gather, no atomics)
//   h = relu(a @ W1 + b1);  z[node] = h . v
__global__ __launch_bounds__(256) void fused1_kernel(
    const float* __restrict__ x, const int* __restrict__ row_ptr,
    const int2* __restrict__ csr, const float* __restrict__ dinv,
    const float* __restrict__ W1, const float* __restrict__ b1,
    const float* __restrict__ v, float* __restrict__ z, int n) {
    __shared__ float lW1[F_IN * HID];  // 32 KB
    __shared__ float lv[HID];
    int t = threadIdx.x;
    for (int i = t; i < F_IN * HID; i += 256) lW1[i] = W1[i];
    if (t < HID) lv[t] = v[t];
    __syncthreads();

    int lane = t & 63;
    int node = blockIdx.x * 4 + (t >> 6);
    if (node >= n) return;

    float di = dinv[node];
    float acc = di * di * x[node * F_IN + lane];

    int beg = row_ptr[node], end = row_ptr[node + 1];
    for (int cb = beg; cb < end; cb += 64) {
        int m = end - cb; if (m > 64) m = 64;
        int ms = 0; float mw = 0.f;
        if (cb + lane < end) {
            int2 e = csr[cb + lane];
            ms = e.x; mw = __int_as_float(e.y);
        }
        for (int j = 0; j < m; ++j) {
            int s = __shfl(ms, j, 64);
            float w = __shfl(mw, j, 64);
            acc += w * x[s * F_IN + lane];
        }
    }

    // GEMV: lane L computes h[2L], h[2L+1]
    float2 h = ((const float2*)b1)[lane];
    #pragma unroll 8
    for (int k = 0; k < F_IN; ++k) {
        float ak = __shfl(acc, k, 64);
        float2 w = ((const float2*)lW1)[k * 64 + lane];
        h.x += ak * w.x;
        h.y += ak * w.y;
    }
    float2 vv = ((const float2*)lv)[lane];
    float hx = h.x > 0.f ? h.x : 0.f;
    float hy = h.y > 0.f ? h.y : 0.f;
    float zp = hx * vv.x + hy * vv.y;
    #pragma unroll
    for (int off = 32; off > 0; off >>= 1) zp += __shfl_xor(zp, off, 64);
    if (lane == 0) z[node] = zp;
}

// Layer 2 (fully collapsed): out[i] = c + di^2*z[i] + sum_in w*z[src]
__global__ void out_kernel(const int* __restrict__ row_ptr, const int2* __restrict__ csr,
                           const float* __restrict__ dinv, const float* __restrict__ z,
                           const float* __restrict__ c, float* __restrict__ out, int n) {
    int i = blockIdx.x * blockDim.x + threadIdx.x;
    if (i < n) {
        float di = dinv[i];
        float acc = c[0] + di * di * z[i];
        int beg = row_ptr[i], end = row_ptr[i + 1];
        for (int e = beg; e < end; ++e) {
            int2 m = csr[e];
            acc += __int_as_float(m.y) * z[m.x];
        }
        out[i] = acc;
    }
}

extern "C" void kernel_launch(void* const* d_in, const int* in_sizes, int n_in,
                              void* d_out, int out_size, void* d_ws, size_t ws_size,
                              hipStream_t stream) {
    const float* x  = (const float*)d_in[0];
    const int*   ei = (const int*)d_in[1];
    const float* W1 = (const float*)d_in[2];
    const float* b1 = (const float*)d_in[3];
    const float* W2 = (const float*)d_in[4];
    const float* b2 = (const float*)d_in[5];
    const float* Wl = (const float*)d_in[6];
    const float* bl = (const float*)d_in[7];
    float* out = (float*)d_out;

    int E = in_sizes[1] / 2;
    const int* src = ei;
    const int* dst = ei + E;

    float* ws     = (float*)d_ws;
    float* dinv   = ws;                       // N
    int*   row_ptr= (int*)(ws + N_NODES);     // N+1 (+pad)
    int*   cursor = row_ptr + N_NODES + 4;    // N   (doubles as cnt)
    int*   bsum   = cursor + N_NODES;         // 256
    float* z      = (float*)(bsum + 256);     // N
    float* v      = z + N_NODES;              // 128
    float* c      = v + HID;                  // 1 (+pad)
    int2*  csr    = (int2*)(c + 4);           // E pairs (8B each)

    int nscan = (N_NODES + SCAN_CHUNK - 1) / SCAN_CHUNK;  // 98

    hipMemsetAsync(cursor, 0, sizeof(int) * N_NODES, stream);  // cnt = 0
    hist_kernel<<<(E + 255) / 256, 256, 0, stream>>>(dst, cursor, E);
    dinv_kernel<<<(N_NODES + 255) / 256, 256, 0, stream>>>(cursor, dinv, N_NODES);
    scan1_kernel<<<nscan, 256, 0, stream>>>(cursor, row_ptr, bsum, N_NODES);
    scan2_kernel<<<1, 64, 0, stream>>>(bsum, nscan);
    scan3_kernel<<<(N_NODES + 255) / 256, 256, 0, stream>>>(row_ptr, bsum, cursor, N_NODES, E);
    permute_kernel<<<(E + 255) / 256, 256, 0, stream>>>(src, dst, dinv, cursor, csr, E);
    prep_kernel<<<1, 128, 0, stream>>>(W2, b2, Wl, bl, v, c);
    fused1_kernel<<<(N_NODES + 3) / 4, 256, 0, stream>>>(x, row_ptr, csr, dinv, W1, b1, v, z, N_NODES);
    out_kernel<<<(N_NODES + 255) / 256, 256, 0, stream>>>(row_ptr, csr, dinv, z, c, out, N_NODES);
}

// Round 3
// 435.564 us; speedup vs baseline: 3.8795x; 1.2520x over previous
//
#include <hip/hip_runtime.h>

// GCN 2-layer, N=100000, F=64, H=128, O=100, out [N,1] fp32.
// out = agg(relu(agg(x)@W1 + b1) . (W2@Wl)) + (b2@Wl + bl)
// agg via CSR-by-dst GATHER (no float atomics).

#define N_NODES 100000
#define F_IN 64
#define HID 128
#define OUT2 100
#define SCAN_CHUNK 1024

__global__ void hist_kernel(const int* __restrict__ dst, int* __restrict__ cnt, int E) {
    int e = blockIdx.x * blockDim.x + threadIdx.x;
    if (e < E) atomicAdd(&cnt[dst[e]], 1);
}

// Block-level exclusive scan over cnt (SCAN_CHUNK/block) + fused dinv compute.
__global__ __launch_bounds__(256) void scan1_kernel(const int* __restrict__ cnt,
                                                    int* __restrict__ row_ptr,
                                                    int* __restrict__ bsum,
                                                    float* __restrict__ dinv, int n) {
    __shared__ int lsum[256];
    int t = threadIdx.x;
    int i0 = blockIdx.x * SCAN_CHUNK + t * 4;
    int a = 0, b = 0, c = 0, d = 0;
    if (i0 < n)     a = cnt[i0];
    if (i0 + 1 < n) b = cnt[i0 + 1];
    if (i0 + 2 < n) c = cnt[i0 + 2];
    if (i0 + 3 < n) d = cnt[i0 + 3];
    if (i0 < n)     dinv[i0]     = rsqrtf((float)a + 1.0f);
    if (i0 + 1 < n) dinv[i0 + 1] = rsqrtf((float)b + 1.0f);
    if (i0 + 2 < n) dinv[i0 + 2] = rsqrtf((float)c + 1.0f);
    if (i0 + 3 < n) dinv[i0 + 3] = rsqrtf((float)d + 1.0f);
    int tsum = a + b + c + d;
    lsum[t] = tsum;
    __syncthreads();
    for (int off = 1; off < 256; off <<= 1) {
        int val = (t >= off) ? lsum[t - off] : 0;
        __syncthreads();
        lsum[t] += val;
        __syncthreads();
    }
    int excl = lsum[t] - tsum;
    if (i0 < n)     row_ptr[i0]     = excl;
    if (i0 + 1 < n) row_ptr[i0 + 1] = excl + a;
    if (i0 + 2 < n) row_ptr[i0 + 2] = excl + a + b;
    if (i0 + 3 < n) row_ptr[i0 + 3] = excl + a + b + c;
    if (t == 255) bsum[blockIdx.x] = lsum[255];
}

// Block 0: serial scan of per-block sums. Block 1: v = W2@Wl, c = b2.Wl + bl.
__global__ void scan2_prep_kernel(int* __restrict__ bsum, int nb,
                                  const float* __restrict__ W2, const float* __restrict__ b2,
                                  const float* __restrict__ Wl, const float* __restrict__ bl,
                                  float* __restrict__ v, float* __restrict__ c) {
    if (blockIdx.x == 0) {
        if (threadIdx.x == 0) {
            int run = 0;
            for (int i = 0; i < nb; ++i) { int t = bsum[i]; bsum[i] = run; run += t; }
        }
    } else {
        int j = threadIdx.x;
        if (j < HID) {
            float acc = 0.f;
            for (int k = 0; k < OUT2; ++k) acc += W2[j * OUT2 + k] * Wl[k];
            v[j] = acc;
        }
        if (j == 0) {
            float acc = bl[0];
            for (int k = 0; k < OUT2; ++k) acc += b2[k] * Wl[k];
            *c = acc;
        }
    }
}

__global__ void scan3_kernel(int* __restrict__ row_ptr, const int* __restrict__ bsum,
                             int* __restrict__ cursor, int n, int E) {
    int i = blockIdx.x * blockDim.x + threadIdx.x;
    if (i < n) {
        int r = row_ptr[i] + bsum[i / SCAN_CHUNK];
        row_ptr[i] = r;
        cursor[i] = r;
    }
    if (i == 0) row_ptr[n] = E;
}

// Scatter edges into CSR slots: csr[pos] = {src, dinv[src]*dinv[dst]}
__global__ void permute_kernel(const int* __restrict__ src, const int* __restrict__ dst,
                               const float* __restrict__ dinv, int* __restrict__ cursor,
                               int2* __restrict__ csr, int E) {
    int e = blockIdx.x * blockDim.x + threadIdx.x;
    if (e < E) {
        int s = src[e], d = dst[e];
        int pos = atomicAdd(&cursor[d], 1);
        int2 m;
        m.x = s;
        m.y = __float_as_int(dinv[s] * dinv[d]);
        csr[pos] = m;
    }
}

// Fused layer 1: one wave per node, 16 waves/block sharing one W1 LDS copy.
// Gather processes 4 edges per float4 load: lane l -> edge group q=l>>4, col=l&15.
// a[f] = di^2*x[node,f] + sum_in w*x[src,f]; h = relu(a@W1+b1); z = h.v
__global__ __launch_bounds__(1024) void fused1_kernel(
    const float4* __restrict__ x4, const int* __restrict__ row_ptr,
    const int2* __restrict__ csr, const float* __restrict__ dinv,
    const float* __restrict__ W1, const float* __restrict__ b1,
    const float* __restrict__ v, float* __restrict__ z, int n) {
    __shared__ float lW1[F_IN * HID];  // 32 KB, shared by 16 waves
    __shared__ float lv[HID];
    int t = threadIdx.x;
    for (int i = t; i < F_IN * HID; i += 1024) lW1[i] = W1[i];
    if (t < HID) lv[t] = v[t];
    __syncthreads();

    int lane = t & 63;
    int node = blockIdx.x * 16 + (t >> 6);
    if (node >= n) return;

    int q   = lane >> 4;   // edge sub-group 0..3
    int col = lane & 15;   // float4 column

    // self-loop term (group 0 only; others init 0)
    float di = dinv[node];
    float4 sv = x4[node * 16 + col];
    float sw = (q == 0) ? di * di : 0.f;
    float4 facc;
    facc.x = sw * sv.x; facc.y = sw * sv.y; facc.z = sw * sv.z; facc.w = sw * sv.w;

    int beg = row_ptr[node], end = row_ptr[node + 1];
    int e0 = beg + q;
    int2 m = make_int2(0, 0x80000000);  // w = -0.0 (unused when invalid)
    if (e0 < end) m = csr[e0];
    for (int cb = beg; cb < end; cb += 4) {
        int2 cur = m;
        int en = cb + 4 + q;
        m = make_int2(0, 0x80000000);
        if (en < end) m = csr[en];        // prefetch next round
        bool valid = (cb + q) < end;
        float w = valid ? __int_as_float(cur.y) : 0.f;
        int s = valid ? cur.x : 0;
        float4 xv = x4[s * 16 + col];
        facc.x += w * xv.x; facc.y += w * xv.y;
        facc.z += w * xv.z; facc.w += w * xv.w;
    }

    // reduce the 4 edge sub-groups: every lane ends with full a[4*col .. 4*col+3]
    facc.x += __shfl_xor(facc.x, 16, 64); facc.y += __shfl_xor(facc.y, 16, 64);
    facc.z += __shfl_xor(facc.z, 16, 64); facc.w += __shfl_xor(facc.w, 16, 64);
    facc.x += __shfl_xor(facc.x, 32, 64); facc.y += __shfl_xor(facc.y, 32, 64);
    facc.z += __shfl_xor(facc.z, 32, 64); facc.w += __shfl_xor(facc.w, 32, 64);

    // GEMV: lane L computes h[2L], h[2L+1]
    float2 h = ((const float2*)b1)[lane];
    #pragma unroll
    for (int k0 = 0; k0 < 16; ++k0) {
        float ax = __shfl(facc.x, k0, 64);
        float ay = __shfl(facc.y, k0, 64);
        float az = __shfl(facc.z, k0, 64);
        float aw = __shfl(facc.w, k0, 64);
        float2 w0 = ((const float2*)lW1)[(4 * k0 + 0) * 64 + lane];
        float2 w1 = ((const float2*)lW1)[(4 * k0 + 1) * 64 + lane];
        float2 w2 = ((const float2*)lW1)[(4 * k0 + 2) * 64 + lane];
        float2 w3 = ((const float2*)lW1)[(4 * k0 + 3) * 64 + lane];
        h.x += ax * w0.x + ay * w1.x + az * w2.x + aw * w3.x;
        h.y += ax * w0.y + ay * w1.y + az * w2.y + aw * w3.y;
    }
    float2 vv = ((const float2*)lv)[lane];
    float hx = h.x > 0.f ? h.x : 0.f;
    float hy = h.y > 0.f ? h.y : 0.f;
    float zp = hx * vv.x + hy * vv.y;
    #pragma unroll
    for (int off = 32; off > 0; off >>= 1) zp += __shfl_xor(zp, off, 64);
    if (lane == 0) z[node] = zp;
}

// Layer 2 (collapsed): out[i] = c + di^2*z[i] + sum_in w*z[src]. 8 lanes/node.
__global__ void out_kernel(const int* __restrict__ row_ptr, const int2* __restrict__ csr,
                           const float* __restrict__ dinv, const float* __restrict__ z,
                           const float* __restrict__ c, float* __restrict__ out, int n) {
    int tid = blockIdx.x * blockDim.x + threadIdx.x;
    int node = tid >> 3;
    int sub = tid & 7;
    if (node >= n) return;
    int beg = row_ptr[node], end = row_ptr[node + 1];
    float acc = 0.f;
    for (int e = beg + sub; e < end; e += 8) {
        int2 m = csr[e];
        acc += __int_as_float(m.y) * z[m.x];
    }
    acc += __shfl_xor(acc, 1, 64);
    acc += __shfl_xor(acc, 2, 64);
    acc += __shfl_xor(acc, 4, 64);
    if (sub == 0) {
        float di = dinv[node];
        out[node] = acc + c[0] + di * di * z[node];
    }
}

extern "C" void kernel_launch(void* const* d_in, const int* in_sizes, int n_in,
                              void* d_out, int out_size, void* d_ws, size_t ws_size,
                              hipStream_t stream) {
    const float* x  = (const float*)d_in[0];
    const int*   ei = (const int*)d_in[1];
    const float* W1 = (const float*)d_in[2];
    const float* b1 = (const float*)d_in[3];
    const float* W2 = (const float*)d_in[4];
    const float* b2 = (const float*)d_in[5];
    const float* Wl = (const float*)d_in[6];
    const float* bl = (const float*)d_in[7];
    float* out = (float*)d_out;

    int E = in_sizes[1] / 2;
    const int* src = ei;
    const int* dst = ei + E;

    float* ws     = (float*)d_ws;
    float* dinv   = ws;                       // N
    int*   row_ptr= (int*)(ws + N_NODES);     // N+1 (+pad)
    int*   cursor = row_ptr + N_NODES + 4;    // N   (doubles as cnt)
    int*   bsum   = cursor + N_NODES;         // 256
    float* z      = (float*)(bsum + 256);     // N
    float* v      = z + N_NODES;              // 128
    float* c      = v + HID;                  // 1 (+pad)
    int2*  csr    = (int2*)(c + 4);           // E pairs (8B each)

    int nscan = (N_NODES + SCAN_CHUNK - 1) / SCAN_CHUNK;  // 98

    hipMemsetAsync(cursor, 0, sizeof(int) * N_NODES, stream);  // cnt = 0
    hist_kernel<<<(E + 255) / 256, 256, 0, stream>>>(dst, cursor, E);
    scan1_kernel<<<nscan, 256, 0, stream>>>(cursor, row_ptr, bsum, dinv, N_NODES);
    scan2_prep_kernel<<<2, 128, 0, stream>>>(bsum, nscan, W2, b2, Wl, bl, v, c);
    scan3_kernel<<<(N_NODES + 255) / 256, 256, 0, stream>>>(row_ptr, bsum, cursor, N_NODES, E);
    permute_kernel<<<(E + 255) / 256, 256, 0, stream>>>(src, dst, dinv, cursor, csr, E);
    fused1_kernel<<<(N_NODES + 15) / 16, 1024, 0, stream>>>(
        (const float4*)x, row_ptr, csr, dinv, W1, b1, v, z, N_NODES);
    out_kernel<<<(N_NODES * 8 + 255) / 256, 256, 0, stream>>>(row_ptr, csr, dinv, z, c, out, N_NODES);
}

// Round 4
// 388.884 us; speedup vs baseline: 4.3452x; 1.1200x over previous
//
#include <hip/hip_runtime.h>

// GCN 2-layer, N=100000, F=64, H=128, O=100, out [N,1] fp32.
// out = agg(relu(agg(x)@W1 + b1) . (W2@Wl)) + (b2@Wl + bl)
// agg via CSR-by-dst GATHER (no float atomics).

#define N_NODES 100000
#define F_IN 64
#define HID 128
#define OUT2 100
#define SCAN_CHUNK 1024

__global__ void hist_kernel(const int* __restrict__ dst, int* __restrict__ cnt, int E) {
    int e = blockIdx.x * blockDim.x + threadIdx.x;
    if (e < E) atomicAdd(&cnt[dst[e]], 1);
}

// Block-level exclusive scan over cnt (SCAN_CHUNK/block) + fused dinv compute.
__global__ __launch_bounds__(256) void scan1_kernel(const int* __restrict__ cnt,
                                                    int* __restrict__ row_ptr,
                                                    int* __restrict__ bsum,
                                                    float* __restrict__ dinv, int n) {
    __shared__ int lsum[256];
    int t = threadIdx.x;
    int i0 = blockIdx.x * SCAN_CHUNK + t * 4;
    int a = 0, b = 0, c = 0, d = 0;
    if (i0 < n)     a = cnt[i0];
    if (i0 + 1 < n) b = cnt[i0 + 1];
    if (i0 + 2 < n) c = cnt[i0 + 2];
    if (i0 + 3 < n) d = cnt[i0 + 3];
    if (i0 < n)     dinv[i0]     = rsqrtf((float)a + 1.0f);
    if (i0 + 1 < n) dinv[i0 + 1] = rsqrtf((float)b + 1.0f);
    if (i0 + 2 < n) dinv[i0 + 2] = rsqrtf((float)c + 1.0f);
    if (i0 + 3 < n) dinv[i0 + 3] = rsqrtf((float)d + 1.0f);
    int tsum = a + b + c + d;
    lsum[t] = tsum;
    __syncthreads();
    for (int off = 1; off < 256; off <<= 1) {
        int val = (t >= off) ? lsum[t - off] : 0;
        __syncthreads();
        lsum[t] += val;
        __syncthreads();
    }
    int excl = lsum[t] - tsum;
    if (i0 < n)     row_ptr[i0]     = excl;
    if (i0 + 1 < n) row_ptr[i0 + 1] = excl + a;
    if (i0 + 2 < n) row_ptr[i0 + 2] = excl + a + b;
    if (i0 + 3 < n) row_ptr[i0 + 3] = excl + a + b + c;
    if (t == 255) bsum[blockIdx.x] = lsum[255];
}

// Block 0: wave-parallel scan of per-block sums (nb<=128, 2/lane).
// Block 1: v = W2@Wl, c = b2.Wl + bl.
__global__ void scan2_prep_kernel(int* __restrict__ bsum, int nb,
                                  const float* __restrict__ W2, const float* __restrict__ b2,
                                  const float* __restrict__ Wl, const float* __restrict__ bl,
                                  float* __restrict__ v, float* __restrict__ c) {
    if (blockIdx.x == 0) {
        int l = threadIdx.x;  // 0..63
        if (l < 64) {
            int i0 = 2 * l;
            int a = (i0 < nb) ? bsum[i0] : 0;
            int b = (i0 + 1 < nb) ? bsum[i0 + 1] : 0;
            int s = a + b;
            int inc = s;
            #pragma unroll
            for (int off = 1; off < 64; off <<= 1) {
                int u = __shfl_up(inc, off, 64);
                if (l >= off) inc += u;
            }
            int excl = inc - s;
            if (i0 < nb)     bsum[i0]     = excl;
            if (i0 + 1 < nb) bsum[i0 + 1] = excl + a;
        }
    } else {
        int j = threadIdx.x;
        if (j < HID) {
            float acc = 0.f;
            for (int k = 0; k < OUT2; ++k) acc += W2[j * OUT2 + k] * Wl[k];
            v[j] = acc;
        }
        if (j == 0) {
            float acc = bl[0];
            for (int k = 0; k < OUT2; ++k) acc += b2[k] * Wl[k];
            *c = acc;
        }
    }
}

__global__ void scan3_kernel(int* __restrict__ row_ptr, const int* __restrict__ bsum,
                             int* __restrict__ cursor, int n, int E) {
    int i = blockIdx.x * blockDim.x + threadIdx.x;
    if (i < n) {
        int r = row_ptr[i] + bsum[i / SCAN_CHUNK];
        row_ptr[i] = r;
        cursor[i] = r;
    }
    if (i == 0) row_ptr[n] = E;
}

// Scatter edges into CSR slots: csr[pos] = {src, dinv[src]*dinv[dst]}
__global__ void permute_kernel(const int* __restrict__ src, const int* __restrict__ dst,
                               const float* __restrict__ dinv, int* __restrict__ cursor,
                               int2* __restrict__ csr, int E) {
    int e = blockIdx.x * blockDim.x + threadIdx.x;
    if (e < E) {
        int s = src[e], d = dst[e];
        int pos = atomicAdd(&cursor[d], 1);
        int2 m;
        m.x = s;
        m.y = __float_as_int(dinv[s] * dinv[d]);
        csr[pos] = m;
    }
}

// Fused layer 1: one wave per node, 8 waves/block sharing one W1 LDS copy.
// Gather: 8 edges per iteration — lane l covers edge groups q=l>>4 and q+4,
// each as a float4 column load (2 independent loads in flight / lane).
// a[f] = di^2*x[node,f] + sum_in w*x[src,f]; h = relu(a@W1+b1); z = h.v
__global__ __launch_bounds__(512) void fused1_kernel(
    const float4* __restrict__ x4, const int* __restrict__ row_ptr,
    const int2* __restrict__ csr, const float* __restrict__ dinv,
    const float* __restrict__ W1, const float* __restrict__ b1,
    const float* __restrict__ v, float* __restrict__ z, int n) {
    __shared__ float lW1[F_IN * HID];  // 32 KB, shared by 8 waves
    __shared__ float lv[HID];
    int t = threadIdx.x;
    for (int i = t; i < (F_IN * HID) / 4; i += 512)
        ((float4*)lW1)[i] = ((const float4*)W1)[i];
    if (t < HID) lv[t] = v[t];
    __syncthreads();

    int lane = t & 63;
    int node = blockIdx.x * 8 + (t >> 6);
    if (node >= n) return;

    int q   = lane >> 4;   // edge sub-group 0..3
    int col = lane & 15;   // float4 column

    // self-loop term (group 0 only; others init 0)
    float di = dinv[node];
    float4 sv = x4[node * 16 + col];
    float sw = (q == 0) ? di * di : 0.f;
    float4 facc;
    facc.x = sw * sv.x; facc.y = sw * sv.y; facc.z = sw * sv.z; facc.w = sw * sv.w;

    int beg = row_ptr[node], end = row_ptr[node + 1];
    int2 m0 = make_int2(0, 0);
    int2 m1 = make_int2(0, 0);
    if (beg + q < end)     m0 = csr[beg + q];
    if (beg + 4 + q < end) m1 = csr[beg + 4 + q];
    for (int cb = beg; cb < end; cb += 8) {
        int2 c0 = m0, c1 = m1;
        bool v0 = (cb + q) < end;
        bool v1 = (cb + 4 + q) < end;
        m0 = make_int2(0, 0);
        m1 = make_int2(0, 0);
        if (cb + 8 + q < end)  m0 = csr[cb + 8 + q];    // prefetch next round
        if (cb + 12 + q < end) m1 = csr[cb + 12 + q];
        float w0 = v0 ? __int_as_float(c0.y) : 0.f;
        float w1 = v1 ? __int_as_float(c1.y) : 0.f;
        int s0 = v0 ? c0.x : 0;
        int s1 = v1 ? c1.x : 0;
        float4 xv0 = x4[s0 * 16 + col];
        float4 xv1 = x4[s1 * 16 + col];
        facc.x += w0 * xv0.x + w1 * xv1.x;
        facc.y += w0 * xv0.y + w1 * xv1.y;
        facc.z += w0 * xv0.z + w1 * xv1.z;
        facc.w += w0 * xv0.w + w1 * xv1.w;
    }

    // reduce the 4 edge sub-groups: every lane ends with full a[4*col .. 4*col+3]
    facc.x += __shfl_xor(facc.x, 16, 64); facc.y += __shfl_xor(facc.y, 16, 64);
    facc.z += __shfl_xor(facc.z, 16, 64); facc.w += __shfl_xor(facc.w, 16, 64);
    facc.x += __shfl_xor(facc.x, 32, 64); facc.y += __shfl_xor(facc.y, 32, 64);
    facc.z += __shfl_xor(facc.z, 32, 64); facc.w += __shfl_xor(facc.w, 32, 64);

    // GEMV: lane L computes h[2L], h[2L+1]
    float2 h = ((const float2*)b1)[lane];
    #pragma unroll
    for (int k0 = 0; k0 < 16; ++k0) {
        float ax = __shfl(facc.x, k0, 64);
        float ay = __shfl(facc.y, k0, 64);
        float az = __shfl(facc.z, k0, 64);
        float aw = __shfl(facc.w, k0, 64);
        float2 w0 = ((const float2*)lW1)[(4 * k0 + 0) * 64 + lane];
        float2 w1 = ((const float2*)lW1)[(4 * k0 + 1) * 64 + lane];
        float2 w2 = ((const float2*)lW1)[(4 * k0 + 2) * 64 + lane];
        float2 w3 = ((const float2*)lW1)[(4 * k0 + 3) * 64 + lane];
        h.x += ax * w0.x + ay * w1.x + az * w2.x + aw * w3.x;
        h.y += ax * w0.y + ay * w1.y + az * w2.y + aw * w3.y;
    }
    float2 vv = ((const float2*)lv)[lane];
    float hx = h.x > 0.f ? h.x : 0.f;
    float hy = h.y > 0.f ? h.y : 0.f;
    float zp = hx * vv.x + hy * vv.y;
    #pragma unroll
    for (int off = 32; off > 0; off >>= 1) zp += __shfl_xor(zp, off, 64);
    if (lane == 0) z[node] = zp;
}

// Layer 2 (collapsed): out[i] = c + di^2*z[i] + sum_in w*z[src]. 8 lanes/node.
__global__ void out_kernel(const int* __restrict__ row_ptr, const int2* __restrict__ csr,
                           const float* __restrict__ dinv, const float* __restrict__ z,
                           const float* __restrict__ c, float* __restrict__ out, int n) {
    int tid = blockIdx.x * blockDim.x + threadIdx.x;
    int node = tid >> 3;
    int sub = tid & 7;
    if (node >= n) return;
    int beg = row_ptr[node], end = row_ptr[node + 1];
    float acc = 0.f;
    for (int e = beg + sub; e < end; e += 8) {
        int2 m = csr[e];
        acc += __int_as_float(m.y) * z[m.x];
    }
    acc += __shfl_xor(acc, 1, 64);
    acc += __shfl_xor(acc, 2, 64);
    acc += __shfl_xor(acc, 4, 64);
    if (sub == 0) {
        float di = dinv[node];
        out[node] = acc + c[0] + di * di * z[node];
    }
}

extern "C" void kernel_launch(void* const* d_in, const int* in_sizes, int n_in,
                              void* d_out, int out_size, void* d_ws, size_t ws_size,
                              hipStream_t stream) {
    const float* x  = (const float*)d_in[0];
    const int*   ei = (const int*)d_in[1];
    const float* W1 = (const float*)d_in[2];
    const float* b1 = (const float*)d_in[3];
    const float* W2 = (const float*)d_in[4];
    const float* b2 = (const float*)d_in[5];
    const float* Wl = (const float*)d_in[6];
    const float* bl = (const float*)d_in[7];
    float* out = (float*)d_out;

    int E = in_sizes[1] / 2;
    const int* src = ei;
    const int* dst = ei + E;

    float* ws     = (float*)d_ws;
    float* dinv   = ws;                       // N
    int*   row_ptr= (int*)(ws + N_NODES);     // N+1 (+pad)
    int*   cursor = row_ptr + N_NODES + 4;    // N   (doubles as cnt)
    int*   bsum   = cursor + N_NODES;         // 256
    float* z      = (float*)(bsum + 256);     // N
    float* v      = z + N_NODES;              // 128
    float* c      = v + HID;                  // 1 (+pad)
    int2*  csr    = (int2*)(c + 4);           // E pairs (8B each)

    int nscan = (N_NODES + SCAN_CHUNK - 1) / SCAN_CHUNK;  // 98

    hipMemsetAsync(cursor, 0, sizeof(int) * N_NODES, stream);  // cnt = 0
    hist_kernel<<<(E + 255) / 256, 256, 0, stream>>>(dst, cursor, E);
    scan1_kernel<<<nscan, 256, 0, stream>>>(cursor, row_ptr, bsum, dinv, N_NODES);
    scan2_prep_kernel<<<2, 128, 0, stream>>>(bsum, nscan, W2, b2, Wl, bl, v, c);
    scan3_kernel<<<(N_NODES + 255) / 256, 256, 0, stream>>>(row_ptr, bsum, cursor, N_NODES, E);
    permute_kernel<<<(E + 255) / 256, 256, 0, stream>>>(src, dst, dinv, cursor, csr, E);
    fused1_kernel<<<(N_NODES + 7) / 8, 512, 0, stream>>>(
        (const float4*)x, row_ptr, csr, dinv, W1, b1, v, z, N_NODES);
    out_kernel<<<(N_NODES * 8 + 255) / 256, 256, 0, stream>>>(row_ptr, csr, dinv, z, c, out, N_NODES);
}